// Round 11
// baseline (169.160 us; speedup 1.0000x reference)
//
#include <hip/hip_runtime.h>
#include <stdint.h>

// VQ-VAE vector quantizer — fp32, NCHW input [64,64,32,32], emb [1024,64].
// r10-proven math (absmax 0.0 five rounds), re-engineered for latency:
//   vq_init: exact np C_k + bf16-E table + maxC in ws (once, not per block)
//   vq_main: 1024 blocks x 64 pts; wave = code-quarter (splitK) x all 64 pts
//     (4 row-groups => 1 B-frag feeds 8 MFMAs). B-frags read DIRECTLY from
//     global bf16-E (L1/L2-hot) — no LDS staging, no barriers in the sweeps.
//   score = G - C/2 via MFMA acc-init => argmin(dist) = argmax(score).
//   sweep1 -> per-point smax; thr = smax - W/2, W/2 = 2^-6*sqrt(A)*emax+6e-5
//     (proven superset window for the EXACT np-fp32 ref argmin).
//   sweep2 -> candidates via ballot + owner-lane writes, per-(pt,quarter)<=8.
//   rescue: tot==1 -> winner; else exact np-fp32 eval; overflow -> full scan.
constexpr int KCODES = 1024;
constexpr int DDIM   = 64;
constexpr int HW     = 1024;
constexpr int NPTS   = 65536;

constexpr int OUT_Q    = 0;
constexpr int OUT_IDX  = 4194304;
constexpr int OUT_LOSS = 4259840;
constexpr int OUT_NLL  = 4259841;

// ws 32-bit-unit offsets
constexpr int WS_LOSS   = 0;
constexpr int WS_TICKET = 1;
constexpr int WS_MAXC   = 2;
constexpr int WS_C      = 16;     // 1024 f : exact np C_k
constexpr int WS_E      = 2048;   // 32768 u32 : bf16-E rows (1024 x 32)

typedef __attribute__((ext_vector_type(8))) short short8v;
typedef __attribute__((ext_vector_type(4))) float float4v;

__device__ __forceinline__ uint16_t f2bf(float f) {   // RNE fp32->bf16
    uint32_t u = __float_as_uint(f);
    return (uint16_t)((u + 0x7fffu + ((u >> 16) & 1u)) >> 16);
}

__device__ __forceinline__ float np_pairwise_sumsq64(const float* a) {
    float r[8];
    #pragma unroll
    for (int j = 0; j < 8; ++j) r[j] = __fmul_rn(a[j], a[j]);
    #pragma unroll
    for (int i = 8; i < 64; i += 8)
        #pragma unroll
        for (int j = 0; j < 8; ++j)
            r[j] = __fadd_rn(r[j], __fmul_rn(a[i + j], a[i + j]));
    return __fadd_rn(__fadd_rn(__fadd_rn(r[0], r[1]), __fadd_rn(r[2], r[3])),
                     __fadd_rn(__fadd_rn(r[4], r[5]), __fadd_rn(r[6], r[7])));
}

// Init: exact C_k, bf16-E table, maxC (LDS reduce — no poison-sensitive
// atomics), loss/ticket zero. One block of 1024 threads.
__global__ __launch_bounds__(1024) void vq_init(const float* __restrict__ emb,
                                                float* __restrict__ ws) {
    __shared__ float smax[16];
    const int k = threadIdx.x;
    float row[DDIM];
    const float4* src = (const float4*)(emb + (size_t)k * DDIM);
    #pragma unroll
    for (int j = 0; j < 16; ++j) ((float4*)row)[j] = src[j];
    float C = np_pairwise_sumsq64(row);
    ws[WS_C + k] = C;
    uint32_t* eb = (uint32_t*)ws + WS_E + (size_t)k * 32;
    #pragma unroll
    for (int j = 0; j < 32; ++j)
        eb[j] = (uint32_t)f2bf(row[2 * j]) | ((uint32_t)f2bf(row[2 * j + 1]) << 16);
    float m = C;
    #pragma unroll
    for (int off = 32; off > 0; off >>= 1) m = fmaxf(m, __shfl_down(m, off, 64));
    if ((k & 63) == 0) smax[k >> 6] = m;
    __syncthreads();
    if (k == 0) {
        float mm = smax[0];
        #pragma unroll
        for (int i = 1; i < 16; ++i) mm = fmaxf(mm, smax[i]);
        ws[WS_MAXC]   = mm;     // emax = sqrt(maxC), taken in vq_main
        ws[WS_LOSS]   = 0.0f;
        ((unsigned*)ws)[WS_TICKET] = 0u;
    }
}

__global__ __launch_bounds__(256, 4) void vq_main(
        const float* __restrict__ inp, const float* __restrict__ emb,
        float* __restrict__ ws, float* __restrict__ out, int nblocks)
{
    __shared__ float    sA[64];
    __shared__ float    sPart[4][64];     // per-quarter score-max per point
    __shared__ float    sThr[64];
    __shared__ uint16_t sCand[64 * 4 * 8];
    __shared__ uint8_t  sCnt[64 * 4];
    __shared__ int      sWin[64];
    __shared__ float    sred[4];

    const int tid  = threadIdx.x;
    const int lane = tid & 63;
    const int wave = tid >> 6;          // = code quarter
    const int col  = lane & 15;
    const int quad = lane >> 4;
    const int base = blockIdx.x * 64;   // 64 points/block, same b for all
    const int b    = base >> 10;
    const int hw0  = base & 1023;

    // ---- prologue: exact A per point (wave 0; coalesced per channel) --------
    if (tid < 64) {
        const float* xin = inp + (size_t)b * DDIM * HW + (hw0 + tid);
        float x[DDIM];
        #pragma unroll
        for (int d = 0; d < DDIM; ++d) x[d] = xin[(size_t)d * HW];
        sA[tid] = np_pairwise_sumsq64(x);
    }

    // ---- A-fragments for 4 row-groups, built directly from global -----------
    short8v a[4][2];
    #pragma unroll
    for (int g = 0; g < 4; ++g) {
        const float* xp = inp + (size_t)b * DDIM * HW + (hw0 + g * 16 + col);
        short8v t0, t1;
        #pragma unroll
        for (int j = 0; j < 8; ++j) {
            t0[j] = (short)f2bf(xp[(size_t)(quad * 8 + j) * HW]);
            t1[j] = (short)f2bf(xp[(size_t)(32 + quad * 8 + j) * HW]);
        }
        a[g][0] = t0; a[g][1] = t1;
    }

    const uint16_t* Eb = (const uint16_t*)((const uint32_t*)ws + WS_E);
    const float*    Cw = ws + WS_C;
    const int k0 = wave * 256;

    // ---- sweep 1: per-point score-max over this wave's 256 codes ------------
    float smaxv[4][4];
    #pragma unroll
    for (int g = 0; g < 4; ++g)
        #pragma unroll
        for (int r = 0; r < 4; ++r) smaxv[g][r] = -3.0e38f;

    #pragma unroll 1
    for (int c2 = 0; c2 < 16; ++c2) {
        const int kc = k0 + c2 * 16 + col;
        const uint16_t* er = Eb + (size_t)kc * DDIM + quad * 8;
        short8v b0 = *(const short8v*)(er);
        short8v b1 = *(const short8v*)(er + 32);
        float ci = Cw[kc] * -0.5f;
        float4v cinit = {ci, ci, ci, ci};
        #pragma unroll
        for (int g = 0; g < 4; ++g) {
            float4v acc = cinit;
            acc = __builtin_amdgcn_mfma_f32_16x16x32_bf16(a[g][0], b0, acc, 0, 0, 0);
            acc = __builtin_amdgcn_mfma_f32_16x16x32_bf16(a[g][1], b1, acc, 0, 0, 0);
            #pragma unroll
            for (int r = 0; r < 4; ++r) smaxv[g][r] = fmaxf(smaxv[g][r], acc[r]);
        }
    }
    #pragma unroll
    for (int g = 0; g < 4; ++g)
        #pragma unroll
        for (int r = 0; r < 4; ++r) {
            float m = smaxv[g][r];
            m = fmaxf(m, __shfl_xor(m, 1, 16));
            m = fmaxf(m, __shfl_xor(m, 2, 16));
            m = fmaxf(m, __shfl_xor(m, 4, 16));
            m = fmaxf(m, __shfl_xor(m, 8, 16));
            if (col == 0) sPart[wave][g * 16 + quad * 4 + r] = m;
        }
    __syncthreads();

    // ---- per-point threshold: smax_global - W/2 -----------------------------
    if (tid < 64) {
        float gm = fmaxf(fmaxf(sPart[0][tid], sPart[1][tid]),
                         fmaxf(sPart[2][tid], sPart[3][tid]));
        float emax = sqrtf(ws[WS_MAXC]);
        sThr[tid] = gm - (0.015625f * sqrtf(sA[tid]) * emax + 6e-5f);
    }
    __syncthreads();

    float thr[4][4];
    #pragma unroll
    for (int g = 0; g < 4; ++g)
        #pragma unroll
        for (int r = 0; r < 4; ++r) thr[g][r] = sThr[g * 16 + quad * 4 + r];

    // ---- sweep 2: candidates (bitwise-identical MFMA, ballot collect) -------
    int cnt[4][4];
    #pragma unroll
    for (int g = 0; g < 4; ++g)
        #pragma unroll
        for (int r = 0; r < 4; ++r) cnt[g][r] = 0;

    #pragma unroll 1
    for (int c2 = 0; c2 < 16; ++c2) {
        const int kc = k0 + c2 * 16 + col;
        const uint16_t* er = Eb + (size_t)kc * DDIM + quad * 8;
        short8v b0 = *(const short8v*)(er);
        short8v b1 = *(const short8v*)(er + 32);
        float ci = Cw[kc] * -0.5f;
        float4v cinit = {ci, ci, ci, ci};
        #pragma unroll
        for (int g = 0; g < 4; ++g) {
            float4v acc = cinit;
            acc = __builtin_amdgcn_mfma_f32_16x16x32_bf16(a[g][0], b0, acc, 0, 0, 0);
            acc = __builtin_amdgcn_mfma_f32_16x16x32_bf16(a[g][1], b1, acc, 0, 0, 0);
            #pragma unroll
            for (int r = 0; r < 4; ++r) {
                unsigned long long bm = __ballot(acc[r] >= thr[g][r]);
                if (col == 0) {                    // owner of point (g,quad,r)
                    unsigned gm = (unsigned)(bm >> (quad * 16)) & 0xffffu;
                    while (gm) {
                        int bit = __ffs(gm) - 1;
                        gm &= gm - 1;
                        int ct = cnt[g][r];
                        if (ct < 8)
                            sCand[((g * 16 + quad * 4 + r) * 4 + wave) * 8 + ct] =
                                (uint16_t)(k0 + c2 * 16 + bit);
                        cnt[g][r] = ct + 1;
                    }
                }
            }
        }
    }
    if (col == 0) {
        #pragma unroll
        for (int g = 0; g < 4; ++g)
            #pragma unroll
            for (int r = 0; r < 4; ++r) {
                int c = cnt[g][r];
                sCnt[(g * 16 + quad * 4 + r) * 4 + wave] = (uint8_t)(c > 255 ? 255 : c);
            }
    }
    __syncthreads();

    // ---- rescue: exact np-fp32 (r3-proven expression) on candidates ---------
    if (tid < 64) {
        const int p = tid, n = base + p;
        int cq[4], tot = 0, cmax = 0;
        #pragma unroll
        for (int q = 0; q < 4; ++q) {
            cq[q] = sCnt[p * 4 + q];
            tot += cq[q];
            cmax = cq[q] > cmax ? cq[q] : cmax;
        }
        int win;
        if (tot == 1) {
            win = 0;
            #pragma unroll
            for (int q = 0; q < 4; ++q)
                if (cq[q]) win = sCand[(p * 4 + q) * 8];
        } else {
            const float* xin = inp + (size_t)b * DDIM * HW + (hw0 + p);
            float x[DDIM];
            #pragma unroll
            for (int d = 0; d < DDIM; ++d) x[d] = xin[(size_t)d * HW];
            const float A = sA[p];
            float bd = 3.0e38f; win = KCODES - 1;
            if (cmax <= 8) {
                #pragma unroll 1
                for (int q = 0; q < 4; ++q) {
                    #pragma unroll 1
                    for (int i = 0; i < cq[q]; ++i) {   // ascending k order
                        int k = sCand[(p * 4 + q) * 8 + i];
                        float e[DDIM];
                        const float4* e4 = (const float4*)(emb + (size_t)k * DDIM);
                        #pragma unroll
                        for (int j = 0; j < 16; ++j) ((float4*)e)[j] = e4[j];
                        float g = 0.f;
                        #pragma unroll
                        for (int d = 0; d < DDIM; ++d) g = fmaf(x[d], e[d], g);
                        float dd = __fadd_rn(__fsub_rn(A, __fmul_rn(2.0f, g)), Cw[k]);
                        if (dd < bd || (dd == bd && k < win)) { bd = dd; win = k; }
                    }
                }
            } else {                                    // overflow safety
                #pragma unroll 1
                for (int k = 0; k < KCODES; ++k) {
                    float e[DDIM];
                    const float4* e4 = (const float4*)(emb + (size_t)k * DDIM);
                    #pragma unroll
                    for (int j = 0; j < 16; ++j) ((float4*)e)[j] = e4[j];
                    float g = 0.f;
                    #pragma unroll
                    for (int d = 0; d < DDIM; ++d) g = fmaf(x[d], e[d], g);
                    float dd = __fadd_rn(__fsub_rn(A, __fmul_rn(2.0f, g)), Cw[k]);
                    if (dd < bd) { bd = dd; win = k; }
                }
            }
        }
        sWin[p] = win;
        out[OUT_IDX + n] = (float)win;
    }
    __syncthreads();

    // ---- epilogue: quantized NCHW + loss (r10-proven) -----------------------
    {
        const int pl = tid & 63, qtr = tid >> 6;
        const int win = sWin[pl];
        const int ch0 = qtr * 16;
        float q[16];
        const float4* q4 = (const float4*)(emb + (size_t)win * DDIM + ch0);
        #pragma unroll
        for (int j = 0; j < 4; ++j) ((float4*)q)[j] = q4[j];
        const size_t off = (size_t)b * DDIM * HW + (size_t)ch0 * HW + (hw0 + pl);
        const float* xin2 = inp + off;
        float* orow = out + off;
        float lacc = 0.f;
        #pragma unroll
        for (int j = 0; j < 16; ++j) {
            float xv = xin2[(size_t)j * HW];
            float diff = __fsub_rn(q[j], xv);
            orow[(size_t)j * HW] = __fadd_rn(xv, diff);   // ref's x + (q - x)
            lacc = fmaf(diff, diff, lacc);
        }
        #pragma unroll
        for (int off2 = 32; off2 > 0; off2 >>= 1) lacc += __shfl_down(lacc, off2, 64);
        if (lane == 0) sred[wave] = lacc;
    }
    __syncthreads();
    if (tid == 0) {
        atomicAdd(ws + WS_LOSS, sred[0] + sred[1] + sred[2] + sred[3]);
        __threadfence();
        unsigned old = atomicAdd((unsigned*)ws + WS_TICKET, 1u);
        if (old == (unsigned)(nblocks - 1)) {
            __threadfence();
            float L = __hip_atomic_load(ws + WS_LOSS, __ATOMIC_RELAXED,
                                        __HIP_MEMORY_SCOPE_AGENT);
            out[OUT_LOSS] = L * (1.25f / 4194304.0f);
            out[OUT_NLL]  = 1.0f;
        }
    }
}

extern "C" void kernel_launch(void* const* d_in, const int* in_sizes, int n_in,
                              void* d_out, int out_size, void* d_ws, size_t ws_size,
                              hipStream_t stream) {
    const float* inp = (const float*)d_in[0];
    const float* emb = (const float*)d_in[1];
    float* out = (float*)d_out;
    float* ws  = (float*)d_ws;

    vq_init<<<1, 1024, 0, stream>>>(emb, ws);
    vq_main<<<NPTS / 64, 256, 0, stream>>>(inp, emb, ws, out, NPTS / 64);
}

// Round 12
// 129.293 us; speedup vs baseline: 1.3083x; 1.3083x over previous
//
#include <hip/hip_runtime.h>
#include <stdint.h>

// VQ-VAE vector quantizer — fp32, NCHW input [64,64,32,32], emb [1024,64].
// r11 machinery (absmax 0.0 six rounds) minus ALL device-scope atomics/fences
// in the hot kernel (suspected ~60us same-cacheline atomic convoy):
//   vq_init (4 blocks): exact np C_k + bf16-E table + per-block maxC slots
//   vq_main (1024 blocks x 64 pts): wave = code-quarter splitK; B-frags read
//     directly from global bf16-E with register double-buffer prefetch;
//     score = G - C/2 (MFMA acc-init) => argmin(dist) = argmax(score);
//     sweep1 -> smax; thr = smax - (2^-6*sqrt(A)*emax + 6e-5) [proven window];
//     sweep2 -> candidates via ballot + owner-lane LDS writes;
//     rescue: tot==1 -> winner, else exact np-fp32 eval, overflow -> full scan;
//     epilogue: quantized NCHW + per-block loss partial (PLAIN STORE).
//   vq_fin (1 block): reduce 1024 partials -> loss, nll.
constexpr int KCODES = 1024;
constexpr int DDIM   = 64;
constexpr int HW     = 1024;
constexpr int NPTS   = 65536;

constexpr int OUT_Q    = 0;
constexpr int OUT_IDX  = 4194304;
constexpr int OUT_LOSS = 4259840;
constexpr int OUT_NLL  = 4259841;

// ws 32-bit-unit offsets
constexpr int WS_MAXC  = 0;       // 4 f   : per-init-block max C
constexpr int WS_C     = 16;      // 1024 f: exact np C_k
constexpr int WS_E     = 2048;    // 32768 u32: bf16-E rows (1024 x 32)
constexpr int WS_PART  = 34816;   // 1024 f: per-block loss partials

typedef __attribute__((ext_vector_type(8))) short short8v;
typedef __attribute__((ext_vector_type(4))) float float4v;

__device__ __forceinline__ uint16_t f2bf(float f) {   // RNE fp32->bf16
    uint32_t u = __float_as_uint(f);
    return (uint16_t)((u + 0x7fffu + ((u >> 16) & 1u)) >> 16);
}

__device__ __forceinline__ float np_pairwise_sumsq64(const float* a) {
    float r[8];
    #pragma unroll
    for (int j = 0; j < 8; ++j) r[j] = __fmul_rn(a[j], a[j]);
    #pragma unroll
    for (int i = 8; i < 64; i += 8)
        #pragma unroll
        for (int j = 0; j < 8; ++j)
            r[j] = __fadd_rn(r[j], __fmul_rn(a[i + j], a[i + j]));
    return __fadd_rn(__fadd_rn(__fadd_rn(r[0], r[1]), __fadd_rn(r[2], r[3])),
                     __fadd_rn(__fadd_rn(r[4], r[5]), __fadd_rn(r[6], r[7])));
}

// 4 blocks x 256 threads: code k = blockIdx*256 + tid
__global__ __launch_bounds__(256) void vq_init(const float* __restrict__ emb,
                                               float* __restrict__ ws) {
    __shared__ float smax[4];
    const int k = blockIdx.x * 256 + threadIdx.x;
    float row[DDIM];
    const float4* src = (const float4*)(emb + (size_t)k * DDIM);
    #pragma unroll
    for (int j = 0; j < 16; ++j) ((float4*)row)[j] = src[j];
    float C = np_pairwise_sumsq64(row);
    ws[WS_C + k] = C;
    uint32_t* eb = (uint32_t*)ws + WS_E + (size_t)k * 32;
    #pragma unroll
    for (int j = 0; j < 32; ++j)
        eb[j] = (uint32_t)f2bf(row[2 * j]) | ((uint32_t)f2bf(row[2 * j + 1]) << 16);
    float m = C;
    #pragma unroll
    for (int off = 32; off > 0; off >>= 1) m = fmaxf(m, __shfl_down(m, off, 64));
    if ((threadIdx.x & 63) == 0) smax[threadIdx.x >> 6] = m;
    __syncthreads();
    if (threadIdx.x == 0)
        ws[WS_MAXC + blockIdx.x] =
            fmaxf(fmaxf(smax[0], smax[1]), fmaxf(smax[2], smax[3]));
}

__global__ __launch_bounds__(256, 4) void vq_main(
        const float* __restrict__ inp, const float* __restrict__ emb,
        float* __restrict__ ws, float* __restrict__ out)
{
    __shared__ float    sA[64];
    __shared__ float    sPart[4][64];
    __shared__ float    sThr[64];
    __shared__ uint16_t sCand[64 * 4 * 8];
    __shared__ uint8_t  sCnt[64 * 4];
    __shared__ int      sWin[64];
    __shared__ float    sred[4];

    const int tid  = threadIdx.x;
    const int lane = tid & 63;
    const int wave = tid >> 6;          // = code quarter
    const int col  = lane & 15;
    const int quad = lane >> 4;
    const int base = blockIdx.x * 64;
    const int b    = base >> 10;
    const int hw0  = base & 1023;

    // ---- prologue: exact A per point (wave 0) -------------------------------
    if (tid < 64) {
        const float* xin = inp + (size_t)b * DDIM * HW + (hw0 + tid);
        float x[DDIM];
        #pragma unroll
        for (int d = 0; d < DDIM; ++d) x[d] = xin[(size_t)d * HW];
        sA[tid] = np_pairwise_sumsq64(x);
    }

    // ---- A-fragments (r8/r11-verified layout) -------------------------------
    short8v a[4][2];
    #pragma unroll
    for (int g = 0; g < 4; ++g) {
        const float* xp = inp + (size_t)b * DDIM * HW + (hw0 + g * 16 + col);
        short8v t0, t1;
        #pragma unroll
        for (int j = 0; j < 8; ++j) {
            t0[j] = (short)f2bf(xp[(size_t)(quad * 8 + j) * HW]);
            t1[j] = (short)f2bf(xp[(size_t)(32 + quad * 8 + j) * HW]);
        }
        a[g][0] = t0; a[g][1] = t1;
    }

    const uint16_t* Eb = (const uint16_t*)((const uint32_t*)ws + WS_E);
    const float*    Cw = ws + WS_C;
    const int k0 = wave * 256;

    // ---- sweep 1: per-point score-max (register double-buffer prefetch) ----
    float smaxv[4][4];
    #pragma unroll
    for (int g = 0; g < 4; ++g)
        #pragma unroll
        for (int r = 0; r < 4; ++r) smaxv[g][r] = -3.0e38f;

    {
        const uint16_t* er0 = Eb + (size_t)(k0 + col) * DDIM + quad * 8;
        short8v b0 = *(const short8v*)(er0);
        short8v b1 = *(const short8v*)(er0 + 32);
        float   ci = Cw[k0 + col] * -0.5f;
        #pragma unroll 1
        for (int c2 = 0; c2 < 16; ++c2) {
            short8v nb0, nb1; float nci;
            if (c2 < 15) {
                const int kn = k0 + (c2 + 1) * 16 + col;
                const uint16_t* er = Eb + (size_t)kn * DDIM + quad * 8;
                nb0 = *(const short8v*)(er);
                nb1 = *(const short8v*)(er + 32);
                nci = Cw[kn] * -0.5f;
            }
            float4v cinit = {ci, ci, ci, ci};
            #pragma unroll
            for (int g = 0; g < 4; ++g) {
                float4v acc = cinit;
                acc = __builtin_amdgcn_mfma_f32_16x16x32_bf16(a[g][0], b0, acc, 0, 0, 0);
                acc = __builtin_amdgcn_mfma_f32_16x16x32_bf16(a[g][1], b1, acc, 0, 0, 0);
                #pragma unroll
                for (int r = 0; r < 4; ++r) smaxv[g][r] = fmaxf(smaxv[g][r], acc[r]);
            }
            b0 = nb0; b1 = nb1; ci = nci;
        }
    }
    #pragma unroll
    for (int g = 0; g < 4; ++g)
        #pragma unroll
        for (int r = 0; r < 4; ++r) {
            float m = smaxv[g][r];
            m = fmaxf(m, __shfl_xor(m, 1, 16));
            m = fmaxf(m, __shfl_xor(m, 2, 16));
            m = fmaxf(m, __shfl_xor(m, 4, 16));
            m = fmaxf(m, __shfl_xor(m, 8, 16));
            if (col == 0) sPart[wave][g * 16 + quad * 4 + r] = m;
        }
    __syncthreads();

    // ---- per-point threshold ------------------------------------------------
    if (tid < 64) {
        float gm = fmaxf(fmaxf(sPart[0][tid], sPart[1][tid]),
                         fmaxf(sPart[2][tid], sPart[3][tid]));
        float mc = fmaxf(fmaxf(ws[WS_MAXC], ws[WS_MAXC + 1]),
                         fmaxf(ws[WS_MAXC + 2], ws[WS_MAXC + 3]));
        sThr[tid] = gm - (0.015625f * sqrtf(sA[tid]) * sqrtf(mc) + 6e-5f);
    }
    __syncthreads();

    float thr[4][4];
    #pragma unroll
    for (int g = 0; g < 4; ++g)
        #pragma unroll
        for (int r = 0; r < 4; ++r) thr[g][r] = sThr[g * 16 + quad * 4 + r];

    // ---- sweep 2: candidates (identical MFMA, ballot collect) ---------------
    int cnt[4][4];
    #pragma unroll
    for (int g = 0; g < 4; ++g)
        #pragma unroll
        for (int r = 0; r < 4; ++r) cnt[g][r] = 0;

    {
        const uint16_t* er0 = Eb + (size_t)(k0 + col) * DDIM + quad * 8;
        short8v b0 = *(const short8v*)(er0);
        short8v b1 = *(const short8v*)(er0 + 32);
        float   ci = Cw[k0 + col] * -0.5f;
        #pragma unroll 1
        for (int c2 = 0; c2 < 16; ++c2) {
            short8v nb0, nb1; float nci;
            if (c2 < 15) {
                const int kn = k0 + (c2 + 1) * 16 + col;
                const uint16_t* er = Eb + (size_t)kn * DDIM + quad * 8;
                nb0 = *(const short8v*)(er);
                nb1 = *(const short8v*)(er + 32);
                nci = Cw[kn] * -0.5f;
            }
            float4v cinit = {ci, ci, ci, ci};
            #pragma unroll
            for (int g = 0; g < 4; ++g) {
                float4v acc = cinit;
                acc = __builtin_amdgcn_mfma_f32_16x16x32_bf16(a[g][0], b0, acc, 0, 0, 0);
                acc = __builtin_amdgcn_mfma_f32_16x16x32_bf16(a[g][1], b1, acc, 0, 0, 0);
                #pragma unroll
                for (int r = 0; r < 4; ++r) {
                    unsigned long long bm = __ballot(acc[r] >= thr[g][r]);
                    if (col == 0) {                    // owner of point (g,quad,r)
                        unsigned gm = (unsigned)(bm >> (quad * 16)) & 0xffffu;
                        while (gm) {
                            int bit = __ffs(gm) - 1;
                            gm &= gm - 1;
                            int ct = cnt[g][r];
                            if (ct < 8)
                                sCand[((g * 16 + quad * 4 + r) * 4 + wave) * 8 + ct] =
                                    (uint16_t)(k0 + c2 * 16 + bit);
                            cnt[g][r] = ct + 1;
                        }
                    }
                }
            }
            b0 = nb0; b1 = nb1; ci = nci;
        }
    }
    if (col == 0) {
        #pragma unroll
        for (int g = 0; g < 4; ++g)
            #pragma unroll
            for (int r = 0; r < 4; ++r) {
                int c = cnt[g][r];
                sCnt[(g * 16 + quad * 4 + r) * 4 + wave] = (uint8_t)(c > 255 ? 255 : c);
            }
    }
    __syncthreads();

    // ---- rescue: exact np-fp32 on candidates --------------------------------
    if (tid < 64) {
        const int p = tid, n = base + p;
        int cq[4], tot = 0, cmax = 0;
        #pragma unroll
        for (int q = 0; q < 4; ++q) {
            cq[q] = sCnt[p * 4 + q];
            tot += cq[q];
            cmax = cq[q] > cmax ? cq[q] : cmax;
        }
        int win;
        if (tot == 1) {
            win = 0;
            #pragma unroll
            for (int q = 0; q < 4; ++q)
                if (cq[q]) win = sCand[(p * 4 + q) * 8];
        } else {
            const float* xin = inp + (size_t)b * DDIM * HW + (hw0 + p);
            float x[DDIM];
            #pragma unroll
            for (int d = 0; d < DDIM; ++d) x[d] = xin[(size_t)d * HW];
            const float A = sA[p];
            float bd = 3.0e38f; win = KCODES - 1;
            if (cmax <= 8) {
                #pragma unroll 1
                for (int q = 0; q < 4; ++q) {
                    #pragma unroll 1
                    for (int i = 0; i < cq[q]; ++i) {   // ascending k order
                        int k = sCand[(p * 4 + q) * 8 + i];
                        float e[DDIM];
                        const float4* e4 = (const float4*)(emb + (size_t)k * DDIM);
                        #pragma unroll
                        for (int j = 0; j < 16; ++j) ((float4*)e)[j] = e4[j];
                        float g = 0.f;
                        #pragma unroll
                        for (int d = 0; d < DDIM; ++d) g = fmaf(x[d], e[d], g);
                        float dd = __fadd_rn(__fsub_rn(A, __fmul_rn(2.0f, g)), Cw[k]);
                        if (dd < bd || (dd == bd && k < win)) { bd = dd; win = k; }
                    }
                }
            } else {                                    // overflow safety
                #pragma unroll 1
                for (int k = 0; k < KCODES; ++k) {
                    float e[DDIM];
                    const float4* e4 = (const float4*)(emb + (size_t)k * DDIM);
                    #pragma unroll
                    for (int j = 0; j < 16; ++j) ((float4*)e)[j] = e4[j];
                    float g = 0.f;
                    #pragma unroll
                    for (int d = 0; d < DDIM; ++d) g = fmaf(x[d], e[d], g);
                    float dd = __fadd_rn(__fsub_rn(A, __fmul_rn(2.0f, g)), Cw[k]);
                    if (dd < bd) { bd = dd; win = k; }
                }
            }
        }
        sWin[p] = win;
        out[OUT_IDX + n] = (float)win;
    }
    __syncthreads();

    // ---- epilogue: quantized NCHW + loss partial (plain store) --------------
    {
        const int pl = tid & 63, qtr = tid >> 6;
        const int win = sWin[pl];
        const int ch0 = qtr * 16;
        float q[16];
        const float4* q4 = (const float4*)(emb + (size_t)win * DDIM + ch0);
        #pragma unroll
        for (int j = 0; j < 4; ++j) ((float4*)q)[j] = q4[j];
        const size_t off = (size_t)b * DDIM * HW + (size_t)ch0 * HW + (hw0 + pl);
        const float* xin2 = inp + off;
        float* orow = out + off;
        float lacc = 0.f;
        #pragma unroll
        for (int j = 0; j < 16; ++j) {
            float xv = xin2[(size_t)j * HW];
            float diff = __fsub_rn(q[j], xv);
            orow[(size_t)j * HW] = __fadd_rn(xv, diff);   // ref's x + (q - x)
            lacc = fmaf(diff, diff, lacc);
        }
        #pragma unroll
        for (int o2 = 32; o2 > 0; o2 >>= 1) lacc += __shfl_down(lacc, o2, 64);
        if (lane == 0) sred[wave] = lacc;
    }
    __syncthreads();
    if (tid == 0)
        ws[WS_PART + blockIdx.x] = sred[0] + sred[1] + sred[2] + sred[3];
}

// 1 block x 256: reduce 1024 partials -> loss; write nll
__global__ __launch_bounds__(256) void vq_fin(const float* __restrict__ ws,
                                              float* __restrict__ out) {
    __shared__ float sred[4];
    const int tid = threadIdx.x;
    float s = 0.f;
    #pragma unroll
    for (int j = 0; j < 4; ++j) s += ws[WS_PART + j * 256 + tid];
    #pragma unroll
    for (int off = 32; off > 0; off >>= 1) s += __shfl_down(s, off, 64);
    if ((tid & 63) == 0) sred[tid >> 6] = s;
    __syncthreads();
    if (tid == 0) {
        float L = sred[0] + sred[1] + sred[2] + sred[3];
        out[OUT_LOSS] = L * (1.25f / 4194304.0f);   // (1+CC)*mean over N*D
        out[OUT_NLL]  = 1.0f;
    }
}

extern "C" void kernel_launch(void* const* d_in, const int* in_sizes, int n_in,
                              void* d_out, int out_size, void* d_ws, size_t ws_size,
                              hipStream_t stream) {
    const float* inp = (const float*)d_in[0];
    const float* emb = (const float*)d_in[1];
    float* out = (float*)d_out;
    float* ws  = (float*)d_ws;

    vq_init<<<4, 256, 0, stream>>>(emb, ws);
    vq_main<<<NPTS / 64, 256, 0, stream>>>(inp, emb, ws, out);
    vq_fin<<<1, 256, 0, stream>>>(ws, out);
}